// Round 3
// baseline (20.701 us; speedup 1.0000x reference)
//
#include <hip/hip_runtime.h>

// h[d,t] = sum_o R[d,o] * exp(glogp[d,o] * t),  glogp = -exp(p+gamma)
// D=2048, ORDER=64, L=2048. Output (1, D, L) float32.
//
// One wave per d. Lane l owns t = 4*l + 256*k + j, j=0..3, k=0..7.
// Per mode: state a = R*lam^(4l+256k); outputs via FMA with uniform
// lam^1, lam^2, lam^3; advance a *= lam^256 once per 4 outputs.
// 39 full-rate VALU ops per 32 outputs per mode (~1.2 ops/elem).

#define DMODEL 2048
#define ORDER  64
#define SEQLEN 2048

__global__ __launch_bounds__(256) void imf_kernel(
    const float* __restrict__ gamma,
    const float* __restrict__ R,
    const float* __restrict__ p,
    float* __restrict__ out)
{
    const int wave = threadIdx.x >> 6;
    const int lane = threadIdx.x & 63;
    const int d = blockIdx.x * 4 + wave;

    const float LOG2E = 1.44269504088896340736f;

    // lane o computes mode-o constants (coalesced loads, 3 exp2 total)
    const float g_o = gamma[d * ORDER + lane];
    const float p_o = p[d * ORDER + lane];
    const float r_o = R[d * ORDER + lane];
    const float gl2    = -__builtin_amdgcn_exp2f((p_o + g_o) * LOG2E) * LOG2E; // log2(lambda)
    const float lam1   = __builtin_amdgcn_exp2f(gl2);
    const float lam2   = lam1 * lam1;
    const float lam3   = lam2 * lam1;
    const float lam256 = __builtin_amdgcn_exp2f(gl2 * 256.0f);

    float acc[8][4];
#pragma unroll
    for (int k = 0; k < 8; ++k)
#pragma unroll
        for (int j = 0; j < 4; ++j) acc[k][j] = 0.0f;

    const float t4 = 4.0f * (float)lane;

#pragma unroll 8
    for (int o = 0; o < 64; ++o) {
        const float c_gl2 = __shfl(gl2, o);
        const float c_r   = __shfl(r_o, o);
        const float m1    = __shfl(lam1, o);
        const float m2    = __shfl(lam2, o);
        const float m3    = __shfl(lam3, o);
        const float L     = __shfl(lam256, o);
        float a = __builtin_amdgcn_exp2f(c_gl2 * t4) * c_r;  // R*lam^(4*lane)
#pragma unroll
        for (int k = 0; k < 8; ++k) {
            acc[k][0] += a;        // v_add
            acc[k][1] += a * m1;   // v_fmac
            acc[k][2] += a * m2;
            acc[k][3] += a * m3;
            a *= L;                // advance 256 steps
        }
    }

    float* od = out + (size_t)d * SEQLEN;
#pragma unroll
    for (int k = 0; k < 8; ++k) {
        float4 v = make_float4(acc[k][0], acc[k][1], acc[k][2], acc[k][3]);
        *reinterpret_cast<float4*>(od + k * 256 + 4 * lane) = v;
    }
}

extern "C" void kernel_launch(void* const* d_in, const int* in_sizes, int n_in,
                              void* d_out, int out_size, void* d_ws, size_t ws_size,
                              hipStream_t stream) {
    const float* gamma = (const float*)d_in[0];
    const float* R     = (const float*)d_in[1];
    const float* p     = (const float*)d_in[2];
    float* out = (float*)d_out;

    dim3 grid(DMODEL / 4);
    dim3 block(256);
    imf_kernel<<<grid, block, 0, stream>>>(gamma, R, p, out);
}

// Round 4
// 17.954 us; speedup vs baseline: 1.1530x; 1.1530x over previous
//
#include <hip/hip_runtime.h>

// h[d,t] = sum_o R[d,o] * lam[d,o]^t,  lam = exp(-exp(p+gamma))
// D=2048, ORDER=64, L=2048. Output (1, D, L) float32.
//
// 4 waves/block: wave covers (d = 2*bid + (w>>1), t-half = w&1).
// Lane l owns t = tbase + 256k + 4l + j (j=0..3, k=0..3).
// Mode constants computed lane-parallel (lane=mode), broadcast via
// per-wave LDS slab (uniform-address ds_read_b128 — no shfl chains).
// Inner: 4 FMA + 1 advance-mul per 4 outputs (1.25 ops/(o,t)).

#define DMODEL 2048
#define ORDER  64
#define SEQLEN 2048

__global__ __launch_bounds__(256) void imf_kernel(
    const float* __restrict__ gamma,
    const float* __restrict__ R,
    const float* __restrict__ p,
    float* __restrict__ out)
{
    const int wave = threadIdx.x >> 6;
    const int lane = threadIdx.x & 63;
    const int d    = blockIdx.x * 2 + (wave >> 1);
    const int th   = wave & 1;
    const float tbase = 1024.0f * (float)th;

    __shared__ float cst[4][ORDER][8];

    const float LOG2E = 1.44269504088896340736f;

    // lane o computes mode-o constants for this wave's t-half
    {
        const float gg = gamma[d * ORDER + lane];
        const float pp = p[d * ORDER + lane];
        const float rr = R[d * ORDER + lane];
        const float gl2 = -__builtin_amdgcn_exp2f((pp + gg) * LOG2E) * LOG2E; // log2(lambda)
        const float m1  = __builtin_amdgcn_exp2f(gl2);
        const float m2  = m1 * m1;
        const float m3  = m2 * m1;
        const float L   = __builtin_amdgcn_exp2f(gl2 * 256.0f);       // lam^256
        const float reff = rr * __builtin_amdgcn_exp2f(gl2 * tbase);  // r * lam^tbase
        float4* c4 = reinterpret_cast<float4*>(&cst[wave][lane][0]);
        c4[0] = make_float4(gl2, reff, m1, m2);
        c4[1] = make_float4(m3, L, 0.0f, 0.0f);
    }
    __syncthreads();

    float acc[4][4];
#pragma unroll
    for (int k = 0; k < 4; ++k)
#pragma unroll
        for (int j = 0; j < 4; ++j) acc[k][j] = 0.0f;

    const float t4 = 4.0f * (float)lane;

#pragma unroll 4
    for (int o = 0; o < 64; ++o) {
        const float4 c0 = *reinterpret_cast<const float4*>(&cst[wave][o][0]);
        const float4 c1 = *reinterpret_cast<const float4*>(&cst[wave][o][4]);
        float a = __builtin_amdgcn_exp2f(c0.x * t4) * c0.y;  // reff * lam^(4*lane)
#pragma unroll
        for (int k = 0; k < 4; ++k) {
            acc[k][0] += a;          // v_add
            acc[k][1] += a * c0.z;   // v_fmac (lam^1)
            acc[k][2] += a * c0.w;   // lam^2
            acc[k][3] += a * c1.x;   // lam^3
            a *= c1.y;               // advance 256
        }
    }

    float* od = out + (size_t)d * SEQLEN + (int)tbase;
#pragma unroll
    for (int k = 0; k < 4; ++k) {
        *reinterpret_cast<float4*>(od + k * 256 + 4 * lane) =
            make_float4(acc[k][0], acc[k][1], acc[k][2], acc[k][3]);
    }
}

extern "C" void kernel_launch(void* const* d_in, const int* in_sizes, int n_in,
                              void* d_out, int out_size, void* d_ws, size_t ws_size,
                              hipStream_t stream) {
    const float* gamma = (const float*)d_in[0];
    const float* R     = (const float*)d_in[1];
    const float* p     = (const float*)d_in[2];
    float* out = (float*)d_out;

    dim3 grid(DMODEL / 2);   // 1024 blocks x 4 waves = 4096 waves
    dim3 block(256);
    imf_kernel<<<grid, block, 0, stream>>>(gamma, R, p, out);
}